// Round 1
// baseline (124.184 us; speedup 1.0000x reference)
//
#include <hip/hip_runtime.h>
#include <math.h>

#define B_TOT 8192
#define N_PTS 512
// floats per batch per tensor = 512*3 = 1536 = 384 float4

// One block per batch. 128 threads, 4 points (12 floats = 3 float4) per thread.
__global__ __launch_bounds__(128) void kabsch_batch(const float* __restrict__ x,
                                                    const float* __restrict__ y,
                                                    float* __restrict__ ws)
{
    const int b = blockIdx.x;
    const int t = threadIdx.x;
    const float4* xb = reinterpret_cast<const float4*>(x) + (size_t)b * 384;
    const float4* yb = reinterpret_cast<const float4*>(y) + (size_t)b * 384;

    float4 fx0 = xb[3*t+0], fx1 = xb[3*t+1], fx2 = xb[3*t+2];
    float4 fy0 = yb[3*t+0], fy1 = yb[3*t+1], fy2 = yb[3*t+2];

    // 4 points x 3 comps
    float px[4][3] = {{fx0.x,fx0.y,fx0.z},{fx0.w,fx1.x,fx1.y},
                      {fx1.z,fx1.w,fx2.x},{fx2.y,fx2.z,fx2.w}};
    float py[4][3] = {{fy0.x,fy0.y,fy0.z},{fy0.w,fy1.x,fy1.y},
                      {fy1.z,fy1.w,fy2.x},{fy2.y,fy2.z,fy2.w}};

    // acc: [0..2] Sx, [3..5] Sy, [6..14] Sxy (d*3+e), [15] Sxx, [16] Syy
    float acc[17];
    #pragma unroll
    for (int k = 0; k < 17; k++) acc[k] = 0.f;

    #pragma unroll
    for (int p = 0; p < 4; p++) {
        #pragma unroll
        for (int d = 0; d < 3; d++) {
            float xv = px[p][d], yv = py[p][d];
            acc[d]     += xv;
            acc[3 + d] += yv;
            acc[15]    += xv * xv;
            acc[16]    += yv * yv;
            #pragma unroll
            for (int e = 0; e < 3; e++)
                acc[6 + d*3 + e] += xv * py[p][e];
        }
    }

    // wave (64-lane) shuffle reduction
    #pragma unroll
    for (int k = 0; k < 17; k++) {
        #pragma unroll
        for (int off = 32; off; off >>= 1)
            acc[k] += __shfl_down(acc[k], off, 64);
    }

    __shared__ float red[2][17];
    const int wave = t >> 6, lane = t & 63;
    if (lane == 0) {
        #pragma unroll
        for (int k = 0; k < 17; k++) red[wave][k] = acc[k];
    }
    __syncthreads();

    if (t == 0) {
        double S[17];
        #pragma unroll
        for (int k = 0; k < 17; k++) S[k] = (double)red[0][k] + (double)red[1][k];

        const double Nn = (double)N_PTS;
        double mx[3] = {S[0]/Nn, S[1]/Nn, S[2]/Nn};
        double my[3] = {S[3]/Nn, S[4]/Nn, S[5]/Nn};

        double C[3][3];
        for (int d = 0; d < 3; d++)
            for (int e = 0; e < 3; e++)
                C[d][e] = S[6 + d*3 + e] - Nn * mx[d] * my[e];

        double sxx = S[15] - Nn*(mx[0]*mx[0] + mx[1]*mx[1] + mx[2]*mx[2]);
        double syy = S[16] - Nn*(my[0]*my[0] + my[1]*my[1] + my[2]*my[2]);

        // K = C^T C (symmetric)
        double K00=0,K01=0,K02=0,K11=0,K12=0,K22=0;
        for (int k = 0; k < 3; k++) {
            K00 += C[k][0]*C[k][0]; K01 += C[k][0]*C[k][1]; K02 += C[k][0]*C[k][2];
            K11 += C[k][1]*C[k][1]; K12 += C[k][1]*C[k][2]; K22 += C[k][2]*C[k][2];
        }

        // closed-form symmetric 3x3 eigenvalues (descending lam1>=lam2>=lam3)
        double q3 = (K00 + K11 + K22) / 3.0;
        double p1 = K01*K01 + K02*K02 + K12*K12;
        double a00 = K00 - q3, a11 = K11 - q3, a22 = K22 - q3;
        double p2 = a00*a00 + a11*a11 + a22*a22 + 2.0*p1;
        double lam1, lam2, lam3;
        if (p2 <= 1e-300) {
            lam1 = lam2 = lam3 = q3;
        } else {
            double pp  = sqrt(p2 / 6.0);
            double ip  = 1.0 / pp;
            double b00 = a00*ip, b11 = a11*ip, b22 = a22*ip;
            double b01 = K01*ip, b02 = K02*ip, b12 = K12*ip;
            double detB = b00*(b11*b22 - b12*b12)
                        - b01*(b01*b22 - b12*b02)
                        + b02*(b01*b12 - b11*b02);
            double r = 0.5 * detB;
            r = fmin(1.0, fmax(-1.0, r));
            double phi = acos(r) / 3.0;
            lam1 = q3 + 2.0*pp*cos(phi);
            lam3 = q3 + 2.0*pp*cos(phi + 2.0943951023931954923);  // +2*pi/3
            lam2 = 3.0*q3 - lam1 - lam3;
        }
        lam1 = fmax(lam1, 0.0); lam2 = fmax(lam2, 0.0); lam3 = fmax(lam3, 0.0);
        double s1 = sqrt(lam1), s2 = sqrt(lam2), s3 = sqrt(lam3);

        double detC = C[0][0]*(C[1][1]*C[2][2] - C[1][2]*C[2][1])
                    - C[0][1]*(C[1][0]*C[2][2] - C[1][2]*C[2][0])
                    + C[0][2]*(C[1][0]*C[2][1] - C[1][1]*C[2][0]);
        double sgn = (detC < 0.0) ? -1.0 : 1.0;
        double trRC = s1 + s2 + sgn * s3;   // = sigma1 + sigma2 + d*sigma3

        ws[b] = (float)(sxx + syy - 2.0 * trRC);
    }
}

__global__ __launch_bounds__(256) void reduce_final(const float* __restrict__ ws,
                                                    float* __restrict__ out)
{
    double s = 0.0;
    for (int i = threadIdx.x; i < B_TOT; i += 256) s += (double)ws[i];
    #pragma unroll
    for (int off = 32; off; off >>= 1) s += __shfl_down(s, off, 64);
    __shared__ double red[4];
    const int wave = threadIdx.x >> 6, lane = threadIdx.x & 63;
    if (lane == 0) red[wave] = s;
    __syncthreads();
    if (threadIdx.x == 0) {
        double tot = red[0] + red[1] + red[2] + red[3];
        out[0] = (float)(tot / ((double)B_TOT * (double)N_PTS * 3.0));
    }
}

extern "C" void kernel_launch(void* const* d_in, const int* in_sizes, int n_in,
                              void* d_out, int out_size, void* d_ws, size_t ws_size,
                              hipStream_t stream) {
    const float* x = (const float*)d_in[0];   // input  (B,N,3) fp32
    const float* y = (const float*)d_in[1];   // target (B,N,3) fp32
    float* out = (float*)d_out;               // scalar fp32
    float* ws  = (float*)d_ws;                // per-batch partials (8192 floats)

    kabsch_batch<<<B_TOT, 128, 0, stream>>>(x, y, ws);
    reduce_final<<<1, 256, 0, stream>>>(ws, out);
}

// Round 2
// 123.438 us; speedup vs baseline: 1.0060x; 1.0060x over previous
//
#include <hip/hip_runtime.h>
#include <math.h>

#define B_TOT 8192
#define N_PTS 512
#define WAVES_PER_BLOCK 4
#define BLK_A (64 * WAVES_PER_BLOCK)

// ---------------- Kernel A: per-batch raw sums (pure fp32, bandwidth) --------
// One wave (64 lanes) per batch; lane handles 8 points = 24 floats = 6 float4.
// acc: [0..2] Sx, [3..5] Sy, [6..14] Sxy (d*3+e), [15] Sxx, [16] Syy
// Output TRANSPOSED: ws[k*B_TOT + b]  (coalesced reads in kernel B)
__global__ __launch_bounds__(BLK_A) void sums_kernel(const float* __restrict__ x,
                                                     const float* __restrict__ y,
                                                     float* __restrict__ ws)
{
    const int wave = threadIdx.x >> 6;
    const int lane = threadIdx.x & 63;
    const int b = blockIdx.x * WAVES_PER_BLOCK + wave;

    const float4* xb = reinterpret_cast<const float4*>(x) + (size_t)b * 384 + 6 * lane;
    const float4* yb = reinterpret_cast<const float4*>(y) + (size_t)b * 384 + 6 * lane;

    union { float4 v[6]; float f[24]; } X, Y;
    #pragma unroll
    for (int i = 0; i < 6; i++) { X.v[i] = xb[i]; Y.v[i] = yb[i]; }

    float acc[17];
    #pragma unroll
    for (int k = 0; k < 17; k++) acc[k] = 0.f;

    #pragma unroll
    for (int p = 0; p < 8; p++) {
        float x0 = X.f[3*p], x1 = X.f[3*p+1], x2 = X.f[3*p+2];
        float y0 = Y.f[3*p], y1 = Y.f[3*p+1], y2 = Y.f[3*p+2];
        acc[0] += x0;  acc[1] += x1;  acc[2] += x2;
        acc[3] += y0;  acc[4] += y1;  acc[5] += y2;
        acc[6]  += x0*y0; acc[7]  += x0*y1; acc[8]  += x0*y2;
        acc[9]  += x1*y0; acc[10] += x1*y1; acc[11] += x1*y2;
        acc[12] += x2*y0; acc[13] += x2*y1; acc[14] += x2*y2;
        acc[15] += x0*x0 + x1*x1 + x2*x2;
        acc[16] += y0*y0 + y1*y1 + y2*y2;
    }

    #pragma unroll
    for (int k = 0; k < 17; k++) {
        #pragma unroll
        for (int off = 32; off; off >>= 1)
            acc[k] += __shfl_down(acc[k], off, 64);
    }

    if (lane == 0) {
        #pragma unroll
        for (int k = 0; k < 17; k++) ws[k * B_TOT + b] = acc[k];
    }
}

// ---------------- Kernel B: per-batch Kabsch via 3x3 eigen-solve (parallel) --
__global__ __launch_bounds__(256) void solve_kernel(const float* __restrict__ ws,
                                                    double* __restrict__ blockSums)
{
    const int b = blockIdx.x * 256 + threadIdx.x;

    double S[17];
    #pragma unroll
    for (int k = 0; k < 17; k++) S[k] = (double)ws[k * B_TOT + b];

    const double Nn = (double)N_PTS;
    double mx[3] = {S[0]/Nn, S[1]/Nn, S[2]/Nn};
    double my[3] = {S[3]/Nn, S[4]/Nn, S[5]/Nn};

    double C[3][3];
    #pragma unroll
    for (int d = 0; d < 3; d++)
        #pragma unroll
        for (int e = 0; e < 3; e++)
            C[d][e] = S[6 + d*3 + e] - Nn * mx[d] * my[e];

    double sxx = S[15] - Nn*(mx[0]*mx[0] + mx[1]*mx[1] + mx[2]*mx[2]);
    double syy = S[16] - Nn*(my[0]*my[0] + my[1]*my[1] + my[2]*my[2]);

    // K = C^T C (symmetric)
    double K00=0,K01=0,K02=0,K11=0,K12=0,K22=0;
    #pragma unroll
    for (int k = 0; k < 3; k++) {
        K00 += C[k][0]*C[k][0]; K01 += C[k][0]*C[k][1]; K02 += C[k][0]*C[k][2];
        K11 += C[k][1]*C[k][1]; K12 += C[k][1]*C[k][2]; K22 += C[k][2]*C[k][2];
    }

    // closed-form symmetric 3x3 eigenvalues
    double q3 = (K00 + K11 + K22) / 3.0;
    double p1 = K01*K01 + K02*K02 + K12*K12;
    double a00 = K00 - q3, a11 = K11 - q3, a22 = K22 - q3;
    double p2 = a00*a00 + a11*a11 + a22*a22 + 2.0*p1;
    double lam1, lam2, lam3;
    if (p2 <= 1e-300) {
        lam1 = lam2 = lam3 = q3;
    } else {
        double pp  = sqrt(p2 / 6.0);
        double ip  = 1.0 / pp;
        double b00 = a00*ip, b11 = a11*ip, b22 = a22*ip;
        double b01 = K01*ip, b02 = K02*ip, b12 = K12*ip;
        double detB = b00*(b11*b22 - b12*b12)
                    - b01*(b01*b22 - b12*b02)
                    + b02*(b01*b12 - b11*b02);
        double r = 0.5 * detB;
        r = fmin(1.0, fmax(-1.0, r));
        double phi = acos(r) / 3.0;
        lam1 = q3 + 2.0*pp*cos(phi);
        lam3 = q3 + 2.0*pp*cos(phi + 2.0943951023931954923);  // +2*pi/3
        lam2 = 3.0*q3 - lam1 - lam3;
    }
    lam1 = fmax(lam1, 0.0); lam2 = fmax(lam2, 0.0); lam3 = fmax(lam3, 0.0);
    double s1 = sqrt(lam1), s2 = sqrt(lam2), s3 = sqrt(lam3);

    double detC = C[0][0]*(C[1][1]*C[2][2] - C[1][2]*C[2][1])
                - C[0][1]*(C[1][0]*C[2][2] - C[1][2]*C[2][0])
                + C[0][2]*(C[1][0]*C[2][1] - C[1][1]*C[2][0]);
    double sgn = (detC < 0.0) ? -1.0 : 1.0;
    double trRC = s1 + s2 + sgn * s3;

    double v = sxx + syy - 2.0 * trRC;

    // block reduction (f64)
    #pragma unroll
    for (int off = 32; off; off >>= 1) v += __shfl_down(v, off, 64);
    __shared__ double red[4];
    const int wave = threadIdx.x >> 6, lane = threadIdx.x & 63;
    if (lane == 0) red[wave] = v;
    __syncthreads();
    if (threadIdx.x == 0)
        blockSums[blockIdx.x] = red[0] + red[1] + red[2] + red[3];
}

// ---------------- Kernel C: final mean ---------------------------------------
__global__ __launch_bounds__(64) void final_kernel(const double* __restrict__ bs,
                                                   float* __restrict__ out)
{
    const int t = threadIdx.x;
    double v = (t < 32) ? bs[t] : 0.0;
    #pragma unroll
    for (int off = 32; off; off >>= 1) v += __shfl_down(v, off, 64);
    if (t == 0)
        out[0] = (float)(v / ((double)B_TOT * (double)N_PTS * 3.0));
}

extern "C" void kernel_launch(void* const* d_in, const int* in_sizes, int n_in,
                              void* d_out, int out_size, void* d_ws, size_t ws_size,
                              hipStream_t stream) {
    const float* x = (const float*)d_in[0];   // input  (B,N,3) fp32
    const float* y = (const float*)d_in[1];   // target (B,N,3) fp32
    float* out = (float*)d_out;

    float*  ws = (float*)d_ws;                              // 17*8192 floats
    double* bs = (double*)((char*)d_ws + 17 * B_TOT * 4);   // 32 doubles (8B-aligned)

    sums_kernel <<<B_TOT / WAVES_PER_BLOCK, BLK_A, 0, stream>>>(x, y, ws);
    solve_kernel<<<B_TOT / 256, 256, 0, stream>>>(ws, bs);
    final_kernel<<<1, 64, 0, stream>>>(bs, out);
}

// Round 3
// 123.129 us; speedup vs baseline: 1.0086x; 1.0025x over previous
//
#include <hip/hip_runtime.h>
#include <math.h>

#define B_TOT 8192
#define N_PTS 512
#define WAVES_PER_BLOCK 4
#define BLK_A (64 * WAVES_PER_BLOCK)

// Full-wave (64-lane) sum via DPP — no DS pipe. Total lands in LANE 63.
// Sequence per AMD GCN cross-lane ops / rocPRIM wave64 reduce:
//   row_shr:1, row_shr:2, row_shr:4, row_shr:8  (within 16-lane rows)
//   row_bcast:15 (0x142), row_bcast:31 (0x143)  (across rows)
// bound_ctrl=true => invalid source lanes read 0 (safe for sum).
__device__ __forceinline__ float dpp_wave_sum(float v) {
    int x;
    x = __builtin_amdgcn_update_dpp(0, __float_as_int(v), 0x111, 0xF, 0xF, true);
    v += __int_as_float(x);
    x = __builtin_amdgcn_update_dpp(0, __float_as_int(v), 0x112, 0xF, 0xF, true);
    v += __int_as_float(x);
    x = __builtin_amdgcn_update_dpp(0, __float_as_int(v), 0x114, 0xF, 0xF, true);
    v += __int_as_float(x);
    x = __builtin_amdgcn_update_dpp(0, __float_as_int(v), 0x118, 0xF, 0xF, true);
    v += __int_as_float(x);
    x = __builtin_amdgcn_update_dpp(0, __float_as_int(v), 0x142, 0xF, 0xF, true);
    v += __int_as_float(x);
    x = __builtin_amdgcn_update_dpp(0, __float_as_int(v), 0x143, 0xF, 0xF, true);
    v += __int_as_float(x);
    return v;  // lane 63 holds the wave total
}

// ---------------- Kernel A: per-batch raw sums (fp32, bandwidth-bound) -------
// One wave per batch; lane handles 8 points = 24 floats = 6 float4.
// acc: [0..2] Sx, [3..5] Sy, [6..14] Sxy (d*3+e), [15] Sxx, [16] Syy
// Output TRANSPOSED: ws[k*B_TOT + b]  (coalesced reads in kernel B)
__global__ __launch_bounds__(BLK_A) void sums_kernel(const float* __restrict__ x,
                                                     const float* __restrict__ y,
                                                     float* __restrict__ ws)
{
    const int wave = threadIdx.x >> 6;
    const int lane = threadIdx.x & 63;
    const int b = blockIdx.x * WAVES_PER_BLOCK + wave;

    const float4* xb = reinterpret_cast<const float4*>(x) + (size_t)b * 384 + 6 * lane;
    const float4* yb = reinterpret_cast<const float4*>(y) + (size_t)b * 384 + 6 * lane;

    union { float4 v[6]; float f[24]; } X, Y;
    #pragma unroll
    for (int i = 0; i < 6; i++) { X.v[i] = xb[i]; Y.v[i] = yb[i]; }

    float acc[17];
    #pragma unroll
    for (int k = 0; k < 17; k++) acc[k] = 0.f;

    #pragma unroll
    for (int p = 0; p < 8; p++) {
        float x0 = X.f[3*p], x1 = X.f[3*p+1], x2 = X.f[3*p+2];
        float y0 = Y.f[3*p], y1 = Y.f[3*p+1], y2 = Y.f[3*p+2];
        acc[0] += x0;  acc[1] += x1;  acc[2] += x2;
        acc[3] += y0;  acc[4] += y1;  acc[5] += y2;
        acc[6]  += x0*y0; acc[7]  += x0*y1; acc[8]  += x0*y2;
        acc[9]  += x1*y0; acc[10] += x1*y1; acc[11] += x1*y2;
        acc[12] += x2*y0; acc[13] += x2*y1; acc[14] += x2*y2;
        acc[15] += x0*x0 + x1*x1 + x2*x2;
        acc[16] += y0*y0 + y1*y1 + y2*y2;
    }

    #pragma unroll
    for (int k = 0; k < 17; k++) acc[k] = dpp_wave_sum(acc[k]);

    if (lane == 63) {
        #pragma unroll
        for (int k = 0; k < 17; k++) ws[k * B_TOT + b] = acc[k];
    }
}

// ---------------- Kernel B: per-batch Kabsch via 3x3 eigen-solve (parallel) --
__global__ __launch_bounds__(256) void solve_kernel(const float* __restrict__ ws,
                                                    double* __restrict__ blockSums)
{
    const int b = blockIdx.x * 256 + threadIdx.x;

    double S[17];
    #pragma unroll
    for (int k = 0; k < 17; k++) S[k] = (double)ws[k * B_TOT + b];

    const double Nn = (double)N_PTS;
    double mx[3] = {S[0]/Nn, S[1]/Nn, S[2]/Nn};
    double my[3] = {S[3]/Nn, S[4]/Nn, S[5]/Nn};

    double C[3][3];
    #pragma unroll
    for (int d = 0; d < 3; d++)
        #pragma unroll
        for (int e = 0; e < 3; e++)
            C[d][e] = S[6 + d*3 + e] - Nn * mx[d] * my[e];

    double sxx = S[15] - Nn*(mx[0]*mx[0] + mx[1]*mx[1] + mx[2]*mx[2]);
    double syy = S[16] - Nn*(my[0]*my[0] + my[1]*my[1] + my[2]*my[2]);

    // K = C^T C (symmetric)
    double K00=0,K01=0,K02=0,K11=0,K12=0,K22=0;
    #pragma unroll
    for (int k = 0; k < 3; k++) {
        K00 += C[k][0]*C[k][0]; K01 += C[k][0]*C[k][1]; K02 += C[k][0]*C[k][2];
        K11 += C[k][1]*C[k][1]; K12 += C[k][1]*C[k][2]; K22 += C[k][2]*C[k][2];
    }

    // closed-form symmetric 3x3 eigenvalues
    double q3 = (K00 + K11 + K22) / 3.0;
    double p1 = K01*K01 + K02*K02 + K12*K12;
    double a00 = K00 - q3, a11 = K11 - q3, a22 = K22 - q3;
    double p2 = a00*a00 + a11*a11 + a22*a22 + 2.0*p1;
    double lam1, lam2, lam3;
    if (p2 <= 1e-300) {
        lam1 = lam2 = lam3 = q3;
    } else {
        double pp  = sqrt(p2 / 6.0);
        double ip  = 1.0 / pp;
        double b00 = a00*ip, b11 = a11*ip, b22 = a22*ip;
        double b01 = K01*ip, b02 = K02*ip, b12 = K12*ip;
        double detB = b00*(b11*b22 - b12*b12)
                    - b01*(b01*b22 - b12*b02)
                    + b02*(b01*b12 - b11*b02);
        double r = 0.5 * detB;
        r = fmin(1.0, fmax(-1.0, r));
        double phi = acos(r) / 3.0;
        lam1 = q3 + 2.0*pp*cos(phi);
        lam3 = q3 + 2.0*pp*cos(phi + 2.0943951023931954923);  // +2*pi/3
        lam2 = 3.0*q3 - lam1 - lam3;
    }
    lam1 = fmax(lam1, 0.0); lam2 = fmax(lam2, 0.0); lam3 = fmax(lam3, 0.0);
    double s1 = sqrt(lam1), s2 = sqrt(lam2), s3 = sqrt(lam3);

    double detC = C[0][0]*(C[1][1]*C[2][2] - C[1][2]*C[2][1])
                - C[0][1]*(C[1][0]*C[2][2] - C[1][2]*C[2][0])
                + C[0][2]*(C[1][0]*C[2][1] - C[1][1]*C[2][0]);
    double sgn = (detC < 0.0) ? -1.0 : 1.0;
    double trRC = s1 + s2 + sgn * s3;

    double v = sxx + syy - 2.0 * trRC;

    // block reduction (f64)
    #pragma unroll
    for (int off = 32; off; off >>= 1) v += __shfl_down(v, off, 64);
    __shared__ double red[4];
    const int wave = threadIdx.x >> 6, lane = threadIdx.x & 63;
    if (lane == 0) red[wave] = v;
    __syncthreads();
    if (threadIdx.x == 0)
        blockSums[blockIdx.x] = red[0] + red[1] + red[2] + red[3];
}

// ---------------- Kernel C: final mean ---------------------------------------
__global__ __launch_bounds__(64) void final_kernel(const double* __restrict__ bs,
                                                   float* __restrict__ out)
{
    const int t = threadIdx.x;
    double v = (t < 32) ? bs[t] : 0.0;
    #pragma unroll
    for (int off = 32; off; off >>= 1) v += __shfl_down(v, off, 64);
    if (t == 0)
        out[0] = (float)(v / ((double)B_TOT * (double)N_PTS * 3.0));
}

extern "C" void kernel_launch(void* const* d_in, const int* in_sizes, int n_in,
                              void* d_out, int out_size, void* d_ws, size_t ws_size,
                              hipStream_t stream) {
    const float* x = (const float*)d_in[0];   // input  (B,N,3) fp32
    const float* y = (const float*)d_in[1];   // target (B,N,3) fp32
    float* out = (float*)d_out;

    float*  ws = (float*)d_ws;                              // 17*8192 floats
    double* bs = (double*)((char*)d_ws + 17 * B_TOT * 4);   // 32 doubles (8B-aligned)

    sums_kernel <<<B_TOT / WAVES_PER_BLOCK, BLK_A, 0, stream>>>(x, y, ws);
    solve_kernel<<<B_TOT / 256, 256, 0, stream>>>(ws, bs);
    final_kernel<<<1, 64, 0, stream>>>(bs, out);
}